// Round 12
// baseline (179.958 us; speedup 1.0000x reference)
//
#include <hip/hip_runtime.h>
#include <math.h>

#define Bn 2
#define Sn 2048
#define Dn 1024
#define Hn 16
#define DKn 64
#define Mn (Bn*Sn)

typedef __bf16 bf16;
typedef __attribute__((ext_vector_type(8))) __bf16 bf16x8;
typedef __attribute__((ext_vector_type(4))) __bf16 bf16x4;
typedef __attribute__((ext_vector_type(4))) float f32x4;

__device__ inline f32x4 mfma16(bf16x8 a, bf16x8 b, f32x4 c) {
    return __builtin_amdgcn_mfma_f32_16x16x32_bf16(a, b, c, 0, 0, 0);
}

typedef __attribute__((address_space(3))) void lds_t;
typedef const __attribute__((address_space(1))) void gbl_t;
__device__ __forceinline__ void glds16(const void* g, void* l) {
    __builtin_amdgcn_global_load_lds((gbl_t*)g, (lds_t*)l, 16, 0, 0);
}

#define WAIT_BAR(N)                                                        \
    asm volatile("s_waitcnt vmcnt(" #N ") lgkmcnt(0)" ::: "memory");       \
    __builtin_amdgcn_s_barrier();

// fragment layout: chunk(m,k8) = ((m>>4)*KT + (k>>5))*64 + ((k>>3)&3)*16 + (m&15)
// each chunk is 8 bf16 (16B). A wave's frag load = 64 consecutive chunks = 1KB.

// ---------- converts -> fragment layout ----------
// 3 fp32 [R][1024] arrays -> bf16 frag layout (R = 4096)
__global__ __launch_bounds__(256)
void conv3(const float* __restrict__ s0, const float* __restrict__ s1,
           const float* __restrict__ s2, bf16* __restrict__ d0,
           bf16* __restrict__ d1, bf16* __restrict__ d2)
{
    const float* s = blockIdx.y == 0 ? s0 : blockIdx.y == 1 ? s1 : s2;
    bf16*       d = blockIdx.y == 0 ? d0 : blockIdx.y == 1 ? d1 : d2;
    int i = (blockIdx.x * 256 + threadIdx.x) * 8;
    int m = i >> 10, k = i & 1023;
    float4 a = *(const float4*)(s + i);
    float4 b = *(const float4*)(s + i + 4);
    bf16x8 o;
    o[0]=(bf16)a.x; o[1]=(bf16)a.y; o[2]=(bf16)a.z; o[3]=(bf16)a.w;
    o[4]=(bf16)b.x; o[5]=(bf16)b.y; o[6]=(bf16)b.z; o[7]=(bf16)b.w;
    size_t dst = ((((size_t)(m >> 4) * 32 + (k >> 5)) * 64)
                  + ((k >> 3) & 3) * 16 + (m & 15)) * 8;
    *(bf16x8*)(d + dst) = o;
}

// 4 fp32 [1024][1024] weights -> bf16 frag layout
__global__ __launch_bounds__(256)
void conv_w(const float* __restrict__ s0, const float* __restrict__ s1,
            const float* __restrict__ s2, const float* __restrict__ s3,
            bf16* __restrict__ d0, bf16* __restrict__ d1,
            bf16* __restrict__ d2, bf16* __restrict__ d3)
{
    const float* s = blockIdx.y == 0 ? s0 : blockIdx.y == 1 ? s1 :
                     blockIdx.y == 2 ? s2 : s3;
    bf16*       d = blockIdx.y == 0 ? d0 : blockIdx.y == 1 ? d1 :
                     blockIdx.y == 2 ? d2 : d3;
    int i = (blockIdx.x * 256 + threadIdx.x) * 8;
    int n = i >> 10, k = i & 1023;
    float4 a = *(const float4*)(s + i);
    float4 b = *(const float4*)(s + i + 4);
    bf16x8 o;
    o[0]=(bf16)a.x; o[1]=(bf16)a.y; o[2]=(bf16)a.z; o[3]=(bf16)a.w;
    o[4]=(bf16)b.x; o[5]=(bf16)b.y; o[6]=(bf16)b.z; o[7]=(bf16)b.w;
    size_t dst = ((((size_t)(n >> 4) * 32 + (k >> 5)) * 64)
                  + ((k >> 3) & 3) * 16 + (n & 15)) * 8;
    *(bf16x8*)(d + dst) = o;
}

// ---------- mask scan ----------
__global__ __launch_bounds__(64)
void mask_scan(const int* __restrict__ mask, int* __restrict__ pos,
               int* __restrict__ cnt)
{
    const int b    = blockIdx.x;
    const int lane = threadIdx.x;
    const int* mb  = mask + b * Sn;
    int loc[32];
    int c = 0;
    #pragma unroll
    for (int e = 0; e < 32; ++e) {
        loc[e] = (mb[lane * 32 + e] != 0) ? 1 : 0;
        c += loc[e];
    }
    int pre = c;
    #pragma unroll
    for (int off = 1; off < 64; off <<= 1) {
        int v = __shfl_up(pre, off);
        if (lane >= off) pre += v;
    }
    int excl  = pre - c;
    int total = __shfl(pre, 63);
    int un = excl;
    int ms = lane * 32 - excl;
    #pragma unroll
    for (int e = 0; e < 32; ++e) {
        int pv;
        if (loc[e]) { pv = un; ++un; } else { pv = total + ms; ++ms; }
        pos[b * Sn + lane * 32 + e] = pv;
    }
    if (lane == 63) cnt[b] = total;
}

// ---------- projection GEMM: LDS-free, fragment-direct ----------
// A,W in frag layout. 128x128 tile, 4 waves (2x2), wave 64x64 = 4x4 frags.
// Per wave-iter: 8 contiguous 1KB global loads (L2-resident) -> 16 MFMA.
// No LDS, no barriers; 16 indep waves/CU hide L2 latency.
__global__ __launch_bounds__(256)
void gemm_proj(const bf16* __restrict__ Aq, const bf16* __restrict__ Ak,
               const bf16* __restrict__ Av, const bf16* __restrict__ Wq,
               const bf16* __restrict__ Wk, const bf16* __restrict__ Wv,
               const float* __restrict__ bq, const float* __restrict__ bk,
               const float* __restrict__ bv, const int* __restrict__ pos,
               bf16* __restrict__ Cq, bf16* __restrict__ Ck, bf16* __restrict__ Cv)
{
    const int bid = blockIdx.x;
    const int l   = (bid & 7) * 96 + (bid >> 3);   // bijective (768 % 8 == 0)
    const int z   = l >> 8;
    const int rem = l & 255;
    const int m0  = (rem >> 3) * 128;
    const int n0  = (rem & 7) * 128;

    const bf16*  A    = z == 0 ? Aq : z == 1 ? Ak : Av;
    const bf16*  W    = z == 0 ? Wq : z == 1 ? Wk : Wv;
    const float* bias = z == 0 ? bq : z == 1 ? bk : bv;
    bf16*        C    = z == 0 ? Cq : z == 1 ? Ck : Cv;

    const int tid = threadIdx.x;
    const int w4 = tid >> 6, ln = tid & 63;
    const int p = ln & 15, g = ln >> 4;
    const int wr = w4 >> 1, wc = w4 & 1;

    // frag stream bases: tile16 index mt = m0/16 + wr*4 + mi
    const bf16* a_base = A + ((size_t)(m0/16 + wr*4) * 32) * 512 + ln * 8;
    const bf16* w_base = W + ((size_t)(n0/16 + wc*4) * 32) * 512 + ln * 8;

    f32x4 acc[4][4];
    #pragma unroll
    for (int mi = 0; mi < 4; ++mi)
        #pragma unroll
        for (int ni = 0; ni < 4; ++ni) acc[mi][ni] = (f32x4){0.f,0.f,0.f,0.f};

    for (int kt = 0; kt < 32; ++kt) {
        bf16x8 af[4], bfr[4];
        #pragma unroll
        for (int mi = 0; mi < 4; ++mi)
            af[mi] = *(const bf16x8*)(a_base + ((size_t)mi*32 + kt) * 512);
        #pragma unroll
        for (int ni = 0; ni < 4; ++ni)
            bfr[ni] = *(const bf16x8*)(w_base + ((size_t)ni*32 + kt) * 512);
        #pragma unroll
        for (int mi = 0; mi < 4; ++mi)
            #pragma unroll
            for (int ni = 0; ni < 4; ++ni)
                acc[mi][ni] = mfma16(af[mi], bfr[ni], acc[mi][ni]);
    }

    if (z == 0) {
        const float osc = 0.18033688011112042f;   // log2(e)/8
        #pragma unroll
        for (int ni = 0; ni < 4; ++ni) {
            int n = n0 + wc*64 + ni*16 + p;
            int h = n >> 6, dk = n & (DKn - 1);
            float bv = bias[n];
            #pragma unroll
            for (int mi = 0; mi < 4; ++mi)
                #pragma unroll
                for (int r = 0; r < 4; ++r) {
                    int m = m0 + wr*64 + mi*16 + 4*g + r;
                    int b = m >> 11, s = m & (Sn - 1);
                    C[(((size_t)(b*Hn + h)*Sn + s)*DKn) + dk] =
                        (bf16)((acc[mi][ni][r] + bv) * osc);
                }
        }
    } else {
        int slots[4][4];
        #pragma unroll
        for (int mi = 0; mi < 4; ++mi)
            #pragma unroll
            for (int r = 0; r < 4; ++r) {
                int m = m0 + wr*64 + mi*16 + 4*g + r;
                int b = m >> 11, s = m & (Sn - 1);
                slots[mi][r] = pos[b*Sn + s];
            }
        if (z == 1) {
            #pragma unroll
            for (int ni = 0; ni < 4; ++ni) {
                int n = n0 + wc*64 + ni*16 + p;
                int h = n >> 6, dk = n & (DKn - 1);
                float bv = bias[n];
                #pragma unroll
                for (int mi = 0; mi < 4; ++mi)
                    #pragma unroll
                    for (int r = 0; r < 4; ++r) {
                        int m = m0 + wr*64 + mi*16 + 4*g + r;
                        int b = m >> 11;
                        C[(((size_t)(b*Hn + h)*Sn + slots[mi][r])*DKn) + dk] =
                            (bf16)(acc[mi][ni][r] + bv);
                    }
            }
        } else {
            #pragma unroll
            for (int ni = 0; ni < 4; ++ni) {
                int n = n0 + wc*64 + ni*16 + p;
                int h = n >> 6, dk = n & (DKn - 1);
                float bv = bias[n];
                #pragma unroll
                for (int mi = 0; mi < 4; ++mi)
                    #pragma unroll
                    for (int r = 0; r < 4; ++r) {
                        int m = m0 + wr*64 + mi*16 + 4*g + r;
                        int b = m >> 11;
                        C[(((size_t)(b*Hn + h)*DKn + dk)*Sn) + slots[mi][r]] =
                            (bf16)(acc[mi][ni][r] + bv);
                    }
            }
        }
    }
}

// ---------- output GEMM: LDS-free, fragment-direct ----------
// ctx (frag layout, written by attn) @ Wo^T + b_o -> fp32 [M][Dn].
// 128(M)x64(N) tile, 4 waves (2x2), wave 64x32 = 4x2 frags. Grid 512.
__global__ __launch_bounds__(256)
void gemm_out(const bf16* __restrict__ A, const bf16* __restrict__ W,
              const float* __restrict__ bias, float* __restrict__ C)
{
    const int bid = blockIdx.x;
    const int l   = (bid & 7) * 64 + (bid >> 3);
    const int m0  = (l >> 4) * 128;
    const int n0  = (l & 15) * 64;

    const int tid = threadIdx.x;
    const int w4 = tid >> 6, ln = tid & 63;
    const int p = ln & 15, g = ln >> 4;
    const int wr = w4 >> 1, wc = w4 & 1;

    const bf16* a_base = A + ((size_t)(m0/16 + wr*4) * 32) * 512 + ln * 8;
    const bf16* w_base = W + ((size_t)(n0/16 + wc*2) * 32) * 512 + ln * 8;

    f32x4 acc[4][2];
    #pragma unroll
    for (int mi = 0; mi < 4; ++mi)
        #pragma unroll
        for (int ni = 0; ni < 2; ++ni) acc[mi][ni] = (f32x4){0.f,0.f,0.f,0.f};

    for (int kt = 0; kt < 32; ++kt) {
        bf16x8 af[4], bfr[2];
        #pragma unroll
        for (int mi = 0; mi < 4; ++mi)
            af[mi] = *(const bf16x8*)(a_base + ((size_t)mi*32 + kt) * 512);
        #pragma unroll
        for (int ni = 0; ni < 2; ++ni)
            bfr[ni] = *(const bf16x8*)(w_base + ((size_t)ni*32 + kt) * 512);
        #pragma unroll
        for (int mi = 0; mi < 4; ++mi)
            #pragma unroll
            for (int ni = 0; ni < 2; ++ni)
                acc[mi][ni] = mfma16(af[mi], bfr[ni], acc[mi][ni]);
    }

    #pragma unroll
    for (int ni = 0; ni < 2; ++ni) {
        int n = n0 + wc*32 + ni*16 + p;
        float bv = bias[n];
        #pragma unroll
        for (int mi = 0; mi < 4; ++mi)
            #pragma unroll
            for (int r = 0; r < 4; ++r) {
                int m = m0 + wr*64 + mi*16 + 4*g + r;
                C[(size_t)m * Dn + n] = acc[mi][ni][r] + bv;
            }
    }
}

// ---------- MFMA flash attention, compacted keys, 3-buffer pipeline ----------
// (r11 structure; epilogue now writes ctx in gemm fragment layout)
__global__ __launch_bounds__(512)
void attn_mfma(const bf16* __restrict__ Q, const bf16* __restrict__ K,
               const bf16* __restrict__ Vt, const int* __restrict__ cnt,
               bf16* __restrict__ ctx)
{
    __shared__ bf16 Ks[3][64][64];
    __shared__ bf16 Vs[3][64][64];
    __shared__ bf16 Ps[8][16][72];

    const int tid  = threadIdx.x;
    const int lane = tid & 63;
    const int w    = tid >> 6;
    const int g    = lane >> 4;
    const int p    = lane & 15;
    const int bh   = blockIdx.y;
    const int b    = bh >> 4;
    const int h    = bh & 15;
    const int q0   = blockIdx.x * 128;

    const int  cntb = cnt[b];
    const bool unif = (cntb == 0);
    const int  nt   = unif ? (Sn / 64) : ((cntb + 63) >> 6);

    const bf16* Qb = Q  + (size_t)bh * Sn * DKn;
    const bf16* Kb = K  + (size_t)bh * Sn * DKn;
    const bf16* Vb = Vt + (size_t)bh * DKn * Sn;

    const int sr   = lane >> 3;
    const int scol = 8 * ((lane & 7) ^ sr);
    const int drow = w * 8 + sr;
    const int swzk = (p & 7) << 3;
    const bf16* gK = Kb + (size_t)drow * DKn + scol;
    const bf16* gV = Vb + (size_t)drow * Sn  + scol;

    bf16x8 aq0, aq1;
    {
        const bf16* qrow = Qb + (size_t)(q0 + w*16 + p) * DKn + 8*g;
        aq0 = *(const bf16x8*)(qrow);
        aq1 = *(const bf16x8*)(qrow + 32);
    }

    f32x4 o[4];
    #pragma unroll
    for (int dt = 0; dt < 4; ++dt) o[dt] = (f32x4){0.f,0.f,0.f,0.f};
    float lq = 0.f;

    glds16(gK,                &Ks[0][w*8][0]);
    glds16(gV,                &Vs[0][w*8][0]);
    glds16(gK + 64*DKn,       &Ks[1][w*8][0]);
    glds16(gV + 64,           &Vs[1][w*8][0]);
    WAIT_BAR(2)

    for (int kt = 0; kt < nt; ++kt) {
        const int cur = kt % 3;
        const bool pre = (kt + 2 < nt);
        if (pre) {
            const int nx = (kt + 2) % 3;
            glds16(gK + (size_t)(kt+2)*64*DKn, &Ks[nx][w*8][0]);
            glds16(gV + (size_t)(kt+2)*64,     &Vs[nx][w*8][0]);
        }

        const bool tail = (!unif) && (kt == nt - 1);
        const int  rem  = cntb - (kt << 6);

        #pragma unroll
        for (int t = 0; t < 4; ++t) {
            f32x4 z = (f32x4){0.f,0.f,0.f,0.f};
            bf16x8 k0 = *(const bf16x8*)&Ks[cur][16*t + p][(8*g)      ^ swzk];
            bf16x8 k1 = *(const bf16x8*)&Ks[cur][16*t + p][(8*g + 32) ^ swzk];
            z = mfma16(k0, aq0, z);
            z = mfma16(k1, aq1, z);
            bf16x4 pk;
            if (unif) {
                pk[0] = (bf16)1.f; pk[1] = (bf16)1.f;
                pk[2] = (bf16)1.f; pk[3] = (bf16)1.f;
                lq += 4.f;
            } else if (tail) {
                int kb = 16*t + 4*g;
                pk[0] = (bf16)(kb + 0 < rem ? exp2f(z[0]) : 0.f);
                pk[1] = (bf16)(kb + 1 < rem ? exp2f(z[1]) : 0.f);
                pk[2] = (bf16)(kb + 2 < rem ? exp2f(z[2]) : 0.f);
                pk[3] = (bf16)(kb + 3 < rem ? exp2f(z[3]) : 0.f);
                lq += (float)pk[0] + (float)pk[1] + (float)pk[2] + (float)pk[3];
            } else {
                pk[0] = (bf16)exp2f(z[0]);
                pk[1] = (bf16)exp2f(z[1]);
                pk[2] = (bf16)exp2f(z[2]);
                pk[3] = (bf16)exp2f(z[3]);
                lq += (float)pk[0] + (float)pk[1] + (float)pk[2] + (float)pk[3];
            }
            *(bf16x4*)&Ps[w][p][16*t + 4*g] = pk;
        }

        bf16x8 pa0 = *(const bf16x8*)&Ps[w][p][8*g];
        bf16x8 pa1 = *(const bf16x8*)&Ps[w][p][32 + 8*g];
        #pragma unroll
        for (int dt = 0; dt < 4; ++dt) {
            bf16x8 v0 = *(const bf16x8*)&Vs[cur][16*dt + p][(8*g)      ^ swzk];
            bf16x8 v1 = *(const bf16x8*)&Vs[cur][16*dt + p][(8*g + 32) ^ swzk];
            o[dt] = mfma16(pa0, v0, o[dt]);
            o[dt] = mfma16(pa1, v1, o[dt]);
        }

        if (pre) { WAIT_BAR(2) }
        else     { WAIT_BAR(0) }
    }

    lq += __shfl_xor(lq, 16);
    lq += __shfl_xor(lq, 32);
    float ld[4];
    #pragma unroll
    for (int r = 0; r < 4; ++r) ld[r] = __shfl(lq, 4*g + r);

    // ctx in gemm fragment layout: row m = b*Sn + s_, col c = h*64+16dt+p
    #pragma unroll
    for (int dt = 0; dt < 4; ++dt)
        #pragma unroll
        for (int r = 0; r < 4; ++r) {
            int m = b*Sn + q0 + w*16 + 4*g + r;
            int c = h*64 + 16*dt + p;
            size_t dst = ((((size_t)(m >> 4) * 32 + (c >> 5)) * 64)
                          + ((c >> 3) & 3) * 16 + (m & 15)) * 8 + (c & 7);
            ctx[dst] = (bf16)(o[dt][r] / ld[r]);
        }
}

extern "C" void kernel_launch(void* const* d_in, const int* in_sizes, int n_in,
                              void* d_out, int out_size, void* d_ws, size_t ws_size,
                              hipStream_t stream) {
    const float* q_in = (const float*)d_in[0];
    const float* k_in = (const float*)d_in[1];
    const float* v_in = (const float*)d_in[2];
    const int*   mask = (const int*)  d_in[3];
    const float* w_q  = (const float*)d_in[4];
    const float* b_q  = (const float*)d_in[5];
    const float* w_k  = (const float*)d_in[6];
    const float* b_k  = (const float*)d_in[7];
    const float* w_v  = (const float*)d_in[8];
    const float* b_v  = (const float*)d_in[9];
    const float* w_o  = (const float*)d_in[10];
    const float* b_o  = (const float*)d_in[11];

    char* ws = (char*)d_ws;
    bf16* Abf_q = (bf16*)(ws);
    bf16* Abf_k = (bf16*)(ws + 8388608);
    bf16* Abf_v = (bf16*)(ws + 16777216);
    bf16* ctx   = (bf16*)(ws);                // aliases Abf_q after proj consumes it
    bf16* Qh    = (bf16*)(ws + 25165824);
    bf16* Kh    = (bf16*)(ws + 33554432);
    bf16* Vt    = (bf16*)(ws + 41943040);
    bf16* Wbf_q = (bf16*)(ws + 50331648);
    bf16* Wbf_k = (bf16*)(ws + 52428800);
    bf16* Wbf_v = (bf16*)(ws + 54525952);
    bf16* Wbf_o = (bf16*)(ws + 56623104);
    int*  pos   = (int*) (ws + 58720256);
    int*  cntb  = (int*) (ws + 58736640);

    dim3 blk(256);
    conv3<<<dim3(2048, 3), blk, 0, stream>>>(q_in, k_in, v_in, Abf_q, Abf_k, Abf_v);
    conv_w<<<dim3(512, 4), blk, 0, stream>>>(w_q, w_k, w_v, w_o,
                                             Wbf_q, Wbf_k, Wbf_v, Wbf_o);
    mask_scan<<<dim3(Bn), dim3(64), 0, stream>>>(mask, pos, cntb);

    gemm_proj<<<dim3(768), blk, 0, stream>>>(
        Abf_q, Abf_k, Abf_v, Wbf_q, Wbf_k, Wbf_v, b_q, b_k, b_v, pos, Qh, Kh, Vt);

    attn_mfma<<<dim3(Sn/128, Bn*Hn), dim3(512), 0, stream>>>(Qh, Kh, Vt, cntb, ctx);

    gemm_out<<<dim3(512), blk, 0, stream>>>(ctx, Wbf_o, b_o, (float*)d_out);
}

// Round 13
// 144.912 us; speedup vs baseline: 1.2418x; 1.2418x over previous
//
#include <hip/hip_runtime.h>
#include <math.h>

#define Bn 2
#define Sn 2048
#define Dn 1024
#define Hn 16
#define DKn 64
#define Mn (Bn*Sn)

typedef __bf16 bf16;
typedef __attribute__((ext_vector_type(8))) __bf16 bf16x8;
typedef __attribute__((ext_vector_type(4))) __bf16 bf16x4;
typedef __attribute__((ext_vector_type(4))) float f32x4;

__device__ inline f32x4 mfma16(bf16x8 a, bf16x8 b, f32x4 c) {
    return __builtin_amdgcn_mfma_f32_16x16x32_bf16(a, b, c, 0, 0, 0);
}

typedef __attribute__((address_space(3))) void lds_t;
typedef const __attribute__((address_space(1))) void gbl_t;
__device__ __forceinline__ void glds16(const void* g, void* l) {
    __builtin_amdgcn_global_load_lds((gbl_t*)g, (lds_t*)l, 16, 0, 0);
}

__device__ __forceinline__ bf16x8 cvt8(float4 a, float4 b) {
    bf16x8 o;
    o[0]=(bf16)a.x; o[1]=(bf16)a.y; o[2]=(bf16)a.z; o[3]=(bf16)a.w;
    o[4]=(bf16)b.x; o[5]=(bf16)b.y; o[6]=(bf16)b.z; o[7]=(bf16)b.w;
    return o;
}

// ---------- mask scan: permutation pos[b][s] (unmasked first), cnt[b] ----------
__global__ __launch_bounds__(64)
void mask_scan(const int* __restrict__ mask, int* __restrict__ pos,
               int* __restrict__ cnt)
{
    const int b    = blockIdx.x;
    const int lane = threadIdx.x;
    const int* mb  = mask + b * Sn;
    int loc[32];
    int c = 0;
    #pragma unroll
    for (int e = 0; e < 32; ++e) {
        loc[e] = (mb[lane * 32 + e] != 0) ? 1 : 0;
        c += loc[e];
    }
    int pre = c;
    #pragma unroll
    for (int off = 1; off < 64; off <<= 1) {
        int v = __shfl_up(pre, off);
        if (lane >= off) pre += v;
    }
    int excl  = pre - c;
    int total = __shfl(pre, 63);
    int un = excl;
    int ms = lane * 32 - excl;
    #pragma unroll
    for (int e = 0; e < 32; ++e) {
        int pv;
        if (loc[e]) { pv = un; ++un; } else { pv = total + ms; ++ms; }
        pos[b * Sn + lane * 32 + e] = pv;
    }
    if (lane == 63) cnt[b] = total;
}

// ---------- projection GEMM, fused fp32->bf16 (reg-staged) ----------
// r9 structure (single-buffer, 2 barriers/iter); staging now loads fp32 A,W
// directly and converts in-register (conv3/conv_w kernels eliminated).
// Next tile's loads are issued AFTER the drain barrier -> fly during MFMA.
// z==0: Q scaled log2(e)/8 -> [B,H,S,DK]; z==1: K rows permuted;
// z==2: V cols permuted -> [B,H,DK,slot].
__global__ __launch_bounds__(256)
void gemm_proj(const float* __restrict__ Aq, const float* __restrict__ Ak,
               const float* __restrict__ Av, const float* __restrict__ Wq,
               const float* __restrict__ Wk, const float* __restrict__ Wv,
               const float* __restrict__ bq, const float* __restrict__ bk,
               const float* __restrict__ bv, const int* __restrict__ pos,
               bf16* __restrict__ Cq, bf16* __restrict__ Ck, bf16* __restrict__ Cv)
{
    __shared__ bf16 As[128][32];
    __shared__ bf16 Ws_[128][32];

    const int bid = blockIdx.x;
    const int l   = (bid & 7) * 96 + (bid >> 3);   // bijective (768 % 8 == 0)
    const int z   = l >> 8;
    const int rem = l & 255;
    const int m0  = (rem >> 3) * 128;
    const int n0  = (rem & 7) * 128;

    const float* A    = z == 0 ? Aq : z == 1 ? Ak : Av;
    const float* W    = z == 0 ? Wq : z == 1 ? Wk : Wv;
    const float* bias = z == 0 ? bq : z == 1 ? bk : bv;
    bf16*        C    = z == 0 ? Cq : z == 1 ? Ck : Cv;

    const int tid = threadIdx.x;
    const int w4 = tid >> 6, ln = tid & 63;
    const int p = ln & 15, g = ln >> 4;
    const int wr = w4 >> 1, wc = w4 & 1;

    const int arow = w4 * 32 + (ln >> 2);
    const int acol = (ln & 3) * 8;
    const float* ga = A + (size_t)(m0 + arow) * Dn + acol;
    const float* gw = W + (size_t)(n0 + arow) * Dn + acol;

    f32x4 acc[4][4];
    #pragma unroll
    for (int mi = 0; mi < 4; ++mi)
        #pragma unroll
        for (int ni = 0; ni < 4; ++ni) acc[mi][ni] = (f32x4){0.f,0.f,0.f,0.f};

    // staging registers for one K-tile (A: 2x8 fp32, W: 2x8 fp32)
    float4 a0, a1, a2, a3, w0, w1, w2, w3;
    a0 = *(const float4*)(ga);            a1 = *(const float4*)(ga + 4);
    a2 = *(const float4*)(ga + 16*Dn);    a3 = *(const float4*)(ga + 16*Dn + 4);
    w0 = *(const float4*)(gw);            w1 = *(const float4*)(gw + 4);
    w2 = *(const float4*)(gw + 16*Dn);    w3 = *(const float4*)(gw + 16*Dn + 4);

    for (int k0 = 0; k0 < Dn; k0 += 32) {
        __syncthreads();                       // prev iter done reading LDS
        *(bf16x8*)&As [arow     ][acol] = cvt8(a0, a1);
        *(bf16x8*)&As [arow + 16][acol] = cvt8(a2, a3);
        *(bf16x8*)&Ws_[arow     ][acol] = cvt8(w0, w1);
        *(bf16x8*)&Ws_[arow + 16][acol] = cvt8(w2, w3);
        __syncthreads();                       // LDS visible

        if (k0 + 32 < Dn) {                    // next tile loads fly during MFMA
            const int k1 = k0 + 32;
            a0 = *(const float4*)(ga + k1);          a1 = *(const float4*)(ga + k1 + 4);
            a2 = *(const float4*)(ga + k1 + 16*Dn);  a3 = *(const float4*)(ga + k1 + 16*Dn + 4);
            w0 = *(const float4*)(gw + k1);          w1 = *(const float4*)(gw + k1 + 4);
            w2 = *(const float4*)(gw + k1 + 16*Dn);  w3 = *(const float4*)(gw + k1 + 16*Dn + 4);
        }

        bf16x8 af[4], bfr[4];
        #pragma unroll
        for (int mi = 0; mi < 4; ++mi)
            af[mi] = *(const bf16x8*)&As[wr*64 + mi*16 + p][g*8];
        #pragma unroll
        for (int ni = 0; ni < 4; ++ni)
            bfr[ni] = *(const bf16x8*)&Ws_[wc*64 + ni*16 + p][g*8];
        #pragma unroll
        for (int mi = 0; mi < 4; ++mi)
            #pragma unroll
            for (int ni = 0; ni < 4; ++ni)
                acc[mi][ni] = mfma16(af[mi], bfr[ni], acc[mi][ni]);
    }

    if (z == 0) {
        const float osc = 0.18033688011112042f;   // log2(e)/8
        #pragma unroll
        for (int ni = 0; ni < 4; ++ni) {
            int n = n0 + wc*64 + ni*16 + p;
            int h = n >> 6, dk = n & (DKn - 1);
            float bv = bias[n];
            #pragma unroll
            for (int mi = 0; mi < 4; ++mi)
                #pragma unroll
                for (int r = 0; r < 4; ++r) {
                    int m = m0 + wr*64 + mi*16 + 4*g + r;
                    int b = m >> 11, s = m & (Sn - 1);
                    C[(((size_t)(b*Hn + h)*Sn + s)*DKn) + dk] =
                        (bf16)((acc[mi][ni][r] + bv) * osc);
                }
        }
    } else {
        int slots[4][4];
        #pragma unroll
        for (int mi = 0; mi < 4; ++mi)
            #pragma unroll
            for (int r = 0; r < 4; ++r) {
                int m = m0 + wr*64 + mi*16 + 4*g + r;
                int b = m >> 11, s = m & (Sn - 1);
                slots[mi][r] = pos[b*Sn + s];
            }
        if (z == 1) {
            #pragma unroll
            for (int ni = 0; ni < 4; ++ni) {
                int n = n0 + wc*64 + ni*16 + p;
                int h = n >> 6, dk = n & (DKn - 1);
                float bv = bias[n];
                #pragma unroll
                for (int mi = 0; mi < 4; ++mi)
                    #pragma unroll
                    for (int r = 0; r < 4; ++r) {
                        int m = m0 + wr*64 + mi*16 + 4*g + r;
                        int b = m >> 11;
                        C[(((size_t)(b*Hn + h)*Sn + slots[mi][r])*DKn) + dk] =
                            (bf16)(acc[mi][ni][r] + bv);
                    }
            }
        } else {
            #pragma unroll
            for (int ni = 0; ni < 4; ++ni) {
                int n = n0 + wc*64 + ni*16 + p;
                int h = n >> 6, dk = n & (DKn - 1);
                float bv = bias[n];
                #pragma unroll
                for (int mi = 0; mi < 4; ++mi)
                    #pragma unroll
                    for (int r = 0; r < 4; ++r) {
                        int m = m0 + wr*64 + mi*16 + 4*g + r;
                        int b = m >> 11;
                        C[(((size_t)(b*Hn + h)*DKn + dk)*Sn) + slots[mi][r]] =
                            (bf16)(acc[mi][ni][r] + bv);
                    }
            }
        }
    }
}

// ---------- output GEMM, fused Wo conversion ----------
// A = ctx bf16 via global_load_lds (r9 pattern); W = w_o fp32 reg-staged.
__global__ __launch_bounds__(256)
void gemm_out(const bf16* __restrict__ A, const float* __restrict__ W,
              const float* __restrict__ bias, float* __restrict__ C)
{
    __shared__ bf16 As[128][32];
    __shared__ bf16 Ws_[64][32];

    const int bid = blockIdx.x;
    const int l   = (bid & 7) * 64 + (bid >> 3);
    const int m0  = (l >> 4) * 128;
    const int n0  = (l & 15) * 64;

    const int tid = threadIdx.x;
    const int w4 = tid >> 6, ln = tid & 63;
    const int p = ln & 15, g = ln >> 4;
    const int wr = w4 >> 1, wc = w4 & 1;

    const int arow = w4 * 32 + (ln >> 2);
    const int acol = (ln & 3) * 8;
    const bf16*  ga = A + (size_t)(m0 + arow) * Dn + acol;
    const int    lwr = w4 * 16 + (ln >> 2);       // local W row 0..63
    const float* gw  = W + (size_t)(n0 + lwr) * Dn + acol;

    f32x4 acc[4][2];
    #pragma unroll
    for (int mi = 0; mi < 4; ++mi)
        #pragma unroll
        for (int ni = 0; ni < 2; ++ni) acc[mi][ni] = (f32x4){0.f,0.f,0.f,0.f};

    float4 w0, w1;
    w0 = *(const float4*)(gw);
    w1 = *(const float4*)(gw + 4);

    for (int k0 = 0; k0 < Dn; k0 += 32) {
        __syncthreads();                       // prev iter done reading LDS
        *(bf16x8*)&Ws_[lwr][acol] = cvt8(w0, w1);
        glds16(ga + k0,          &As[w4*32     ][0]);
        glds16(ga + k0 + 16*Dn,  &As[w4*32 + 16][0]);
        __syncthreads();                       // drains glds16 + ds_write

        if (k0 + 32 < Dn) {                    // next W loads fly during MFMA
            w0 = *(const float4*)(gw + k0 + 32);
            w1 = *(const float4*)(gw + k0 + 36);
        }

        bf16x8 af[4], bfr[2];
        #pragma unroll
        for (int mi = 0; mi < 4; ++mi)
            af[mi] = *(const bf16x8*)&As[wr*64 + mi*16 + p][g*8];
        #pragma unroll
        for (int ni = 0; ni < 2; ++ni)
            bfr[ni] = *(const bf16x8*)&Ws_[wc*32 + ni*16 + p][g*8];
        #pragma unroll
        for (int mi = 0; mi < 4; ++mi)
            #pragma unroll
            for (int ni = 0; ni < 2; ++ni)
                acc[mi][ni] = mfma16(af[mi], bfr[ni], acc[mi][ni]);
    }

    #pragma unroll
    for (int ni = 0; ni < 2; ++ni) {
        int n = n0 + wc*32 + ni*16 + p;
        float bv = bias[n];
        #pragma unroll
        for (int mi = 0; mi < 4; ++mi)
            #pragma unroll
            for (int r = 0; r < 4; ++r) {
                int m = m0 + wr*64 + mi*16 + 4*g + r;
                C[(size_t)m * Dn + n] = acc[mi][ni][r] + bv;
            }
    }
}

// ---------- MFMA flash attention on COMPACTED keys (r9 exact) ----------
__global__ __launch_bounds__(512)
void attn_mfma(const bf16* __restrict__ Q, const bf16* __restrict__ K,
               const bf16* __restrict__ Vt, const int* __restrict__ cnt,
               bf16* __restrict__ ctx)
{
    __shared__ bf16 Ks[2][64][64];
    __shared__ bf16 Vs[2][64][64];
    __shared__ bf16 Ps[8][16][72];

    const int tid  = threadIdx.x;
    const int lane = tid & 63;
    const int w    = tid >> 6;
    const int g    = lane >> 4;
    const int p    = lane & 15;
    const int bh   = blockIdx.y;
    const int b    = bh >> 4;
    const int h    = bh & 15;
    const int q0   = blockIdx.x * 128;

    const int  cntb = cnt[b];
    const bool unif = (cntb == 0);
    const int  nt   = unif ? (Sn / 64) : ((cntb + 63) >> 6);

    const bf16* Qb = Q  + (size_t)bh * Sn * DKn;
    const bf16* Kb = K  + (size_t)bh * Sn * DKn;
    const bf16* Vb = Vt + (size_t)bh * DKn * Sn;

    const int sr   = lane >> 3;
    const int scol = 8 * ((lane & 7) ^ sr);
    const int drow = w * 8 + sr;
    const int swzk = (p & 7) << 3;
    const bf16* gK = Kb + (size_t)drow * DKn + scol;
    const bf16* gV = Vb + (size_t)drow * Sn  + scol;

    bf16x8 aq0, aq1;
    {
        const bf16* qrow = Qb + (size_t)(q0 + w*16 + p) * DKn + 8*g;
        aq0 = *(const bf16x8*)(qrow);
        aq1 = *(const bf16x8*)(qrow + 32);
    }

    f32x4 o[4];
    #pragma unroll
    for (int dt = 0; dt < 4; ++dt) o[dt] = (f32x4){0.f,0.f,0.f,0.f};
    float lq = 0.f;

    glds16(gK, &Ks[0][w*8][0]);
    glds16(gV, &Vs[0][w*8][0]);
    __syncthreads();

    int bf = 0;
    for (int kt = 0; kt < nt; ++kt) {
        if (kt + 1 < nt) {
            glds16(gK + (size_t)(kt+1)*64*DKn, &Ks[bf^1][w*8][0]);
            glds16(gV + (size_t)(kt+1)*64,     &Vs[bf^1][w*8][0]);
        }

        const bool tail = (!unif) && (kt == nt - 1);
        const int  rem  = cntb - (kt << 6);

        #pragma unroll
        for (int t = 0; t < 4; ++t) {
            f32x4 z = (f32x4){0.f,0.f,0.f,0.f};
            bf16x8 k0 = *(const bf16x8*)&Ks[bf][16*t + p][(8*g)      ^ swzk];
            bf16x8 k1 = *(const bf16x8*)&Ks[bf][16*t + p][(8*g + 32) ^ swzk];
            z = mfma16(k0, aq0, z);
            z = mfma16(k1, aq1, z);
            bf16x4 pk;
            if (unif) {
                pk[0] = (bf16)1.f; pk[1] = (bf16)1.f;
                pk[2] = (bf16)1.f; pk[3] = (bf16)1.f;
                lq += 4.f;
            } else if (tail) {
                int kb = 16*t + 4*g;
                pk[0] = (bf16)(kb + 0 < rem ? exp2f(z[0]) : 0.f);
                pk[1] = (bf16)(kb + 1 < rem ? exp2f(z[1]) : 0.f);
                pk[2] = (bf16)(kb + 2 < rem ? exp2f(z[2]) : 0.f);
                pk[3] = (bf16)(kb + 3 < rem ? exp2f(z[3]) : 0.f);
                lq += (float)pk[0] + (float)pk[1] + (float)pk[2] + (float)pk[3];
            } else {
                pk[0] = (bf16)exp2f(z[0]);
                pk[1] = (bf16)exp2f(z[1]);
                pk[2] = (bf16)exp2f(z[2]);
                pk[3] = (bf16)exp2f(z[3]);
                lq += (float)pk[0] + (float)pk[1] + (float)pk[2] + (float)pk[3];
            }
            *(bf16x4*)&Ps[w][p][16*t + 4*g] = pk;
        }

        bf16x8 pa0 = *(const bf16x8*)&Ps[w][p][8*g];
        bf16x8 pa1 = *(const bf16x8*)&Ps[w][p][32 + 8*g];
        #pragma unroll
        for (int dt = 0; dt < 4; ++dt) {
            bf16x8 v0 = *(const bf16x8*)&Vs[bf][16*dt + p][(8*g)      ^ swzk];
            bf16x8 v1 = *(const bf16x8*)&Vs[bf][16*dt + p][(8*g + 32) ^ swzk];
            o[dt] = mfma16(pa0, v0, o[dt]);
            o[dt] = mfma16(pa1, v1, o[dt]);
        }

        __syncthreads();
        bf ^= 1;
    }

    lq += __shfl_xor(lq, 16);
    lq += __shfl_xor(lq, 32);
    float ld[4];
    #pragma unroll
    for (int r = 0; r < 4; ++r) ld[r] = __shfl(lq, 4*g + r);

    #pragma unroll
    for (int dt = 0; dt < 4; ++dt)
        #pragma unroll
        for (int r = 0; r < 4; ++r) {
            int s_ = q0 + w*16 + 4*g + r;
            ctx[(size_t)(b*Sn + s_) * Dn + h*64 + 16*dt + p] =
                (bf16)(o[dt][r] / ld[r]);
        }
}

extern "C" void kernel_launch(void* const* d_in, const int* in_sizes, int n_in,
                              void* d_out, int out_size, void* d_ws, size_t ws_size,
                              hipStream_t stream) {
    const float* q_in = (const float*)d_in[0];
    const float* k_in = (const float*)d_in[1];
    const float* v_in = (const float*)d_in[2];
    const int*   mask = (const int*)  d_in[3];
    const float* w_q  = (const float*)d_in[4];
    const float* b_q  = (const float*)d_in[5];
    const float* w_k  = (const float*)d_in[6];
    const float* b_k  = (const float*)d_in[7];
    const float* w_v  = (const float*)d_in[8];
    const float* b_v  = (const float*)d_in[9];
    const float* w_o  = (const float*)d_in[10];
    const float* b_o  = (const float*)d_in[11];

    // ws: ctx 8.39MB | Qh 8.39 | Kh 8.39 | Vt 8.39 | pos 16KB | cnt. Total ~33.6MB.
    char* ws = (char*)d_ws;
    bf16* ctx  = (bf16*)(ws);
    bf16* Qh   = (bf16*)(ws + 8388608);
    bf16* Kh   = (bf16*)(ws + 16777216);
    bf16* Vt   = (bf16*)(ws + 25165824);
    int*  pos  = (int*) (ws + 33554432);
    int*  cntb = (int*) (ws + 33570816);

    dim3 blk(256);
    mask_scan<<<dim3(Bn), dim3(64), 0, stream>>>(mask, pos, cntb);

    gemm_proj<<<dim3(768), blk, 0, stream>>>(
        q_in, k_in, v_in, w_q, w_k, w_v, b_q, b_k, b_v, pos, Qh, Kh, Vt);

    attn_mfma<<<dim3(Sn/128, Bn*Hn), dim3(512), 0, stream>>>(Qh, Kh, Vt, cntb, ctx);

    gemm_out<<<dim3(512), blk, 0, stream>>>(ctx, w_o, b_o, (float*)d_out);
}

// Round 14
// 120.683 us; speedup vs baseline: 1.4912x; 1.2008x over previous
//
#include <hip/hip_runtime.h>
#include <math.h>

#define Bn 2
#define Sn 2048
#define Dn 1024
#define Hn 16
#define DKn 64
#define Mn (Bn*Sn)

typedef __bf16 bf16;
typedef __attribute__((ext_vector_type(8))) __bf16 bf16x8;
typedef __attribute__((ext_vector_type(4))) __bf16 bf16x4;
typedef __attribute__((ext_vector_type(4))) float f32x4;

__device__ inline f32x4 mfma16(bf16x8 a, bf16x8 b, f32x4 c) {
    return __builtin_amdgcn_mfma_f32_16x16x32_bf16(a, b, c, 0, 0, 0);
}

typedef __attribute__((address_space(3))) void lds_t;
typedef const __attribute__((address_space(1))) void gbl_t;
__device__ __forceinline__ void glds16(const void* g, void* l) {
    __builtin_amdgcn_global_load_lds((gbl_t*)g, (lds_t*)l, 16, 0, 0);
}

__device__ __forceinline__ bf16x8 cvt8(float4 a, float4 b) {
    bf16x8 o;
    o[0]=(bf16)a.x; o[1]=(bf16)a.y; o[2]=(bf16)a.z; o[3]=(bf16)a.w;
    o[4]=(bf16)b.x; o[5]=(bf16)b.y; o[6]=(bf16)b.z; o[7]=(bf16)b.w;
    return o;
}

// ---------- mask scan: INVERSE permutation inv[b][j] = source row of slot j ----------
// (unmasked rows fill slots [0,cnt), masked rows fill [cnt,Sn)); cnt[b].
__global__ __launch_bounds__(64)
void mask_scan(const int* __restrict__ mask, int* __restrict__ inv,
               int* __restrict__ cnt)
{
    const int b    = blockIdx.x;
    const int lane = threadIdx.x;
    const int* mb  = mask + b * Sn;
    int loc[32];
    int c = 0;
    #pragma unroll
    for (int e = 0; e < 32; ++e) {
        loc[e] = (mb[lane * 32 + e] != 0) ? 1 : 0;
        c += loc[e];
    }
    int pre = c;
    #pragma unroll
    for (int off = 1; off < 64; off <<= 1) {
        int v = __shfl_up(pre, off);
        if (lane >= off) pre += v;
    }
    int excl  = pre - c;
    int total = __shfl(pre, 63);
    int un = excl;
    int ms = lane * 32 - excl;
    #pragma unroll
    for (int e = 0; e < 32; ++e) {
        int s = lane * 32 + e;
        if (loc[e]) { inv[b * Sn + un] = s;           ++un; }
        else        { inv[b * Sn + total + ms] = s;   ++ms; }
    }
    if (lane == 63) cnt[b] = total;
}

// ---------- projection GEMM, fused fp32->bf16, mask-compacted K/V ----------
// z==0: Q (all rows) scaled log2(e)/8 -> [B,H,S,DK].
// z==1: K — block owns output SLOTS [s0,s0+128) of batch b; input rows
//        gathered via inv; blocks with s0 >= eff_cnt exit. Out [B,H,slot,DK].
// z==2: V — same gather; out [B,H,DK,slot].
__global__ __launch_bounds__(256)
void gemm_proj(const float* __restrict__ Aq, const float* __restrict__ Ak,
               const float* __restrict__ Av, const float* __restrict__ Wq,
               const float* __restrict__ Wk, const float* __restrict__ Wv,
               const float* __restrict__ bq, const float* __restrict__ bk,
               const float* __restrict__ bv, const int* __restrict__ inv,
               const int* __restrict__ cnt,
               bf16* __restrict__ Cq, bf16* __restrict__ Ck, bf16* __restrict__ Cv)
{
    __shared__ bf16 As[128][32];
    __shared__ bf16 Ws_[128][32];

    const int bid = blockIdx.x;
    const int l   = (bid & 7) * 96 + (bid >> 3);   // bijective (768 % 8 == 0)
    const int z   = l >> 8;
    const int rem = l & 255;
    const int mt  = rem >> 3;            // 0..31
    const int n0  = (rem & 7) * 128;
    const int m0  = mt * 128;
    const int bb  = mt >> 4;             // batch (m-tiles 0-15 -> b0, 16-31 -> b1)
    const int s0  = (mt & 15) * 128;     // slot base (z>=1)

    if (z >= 1) {
        int eff = cnt[bb];
        if (eff == 0) eff = Sn;          // cnt==0: uniform path needs ALL slots
        if (s0 >= eff) return;           // slots never read by attention
    }

    const float* A    = z == 0 ? Aq : z == 1 ? Ak : Av;
    const float* W    = z == 0 ? Wq : z == 1 ? Wk : Wv;
    const float* bias = z == 0 ? bq : z == 1 ? bk : bv;
    bf16*        C    = z == 0 ? Cq : z == 1 ? Ck : Cv;

    const int tid = threadIdx.x;
    const int w4 = tid >> 6, ln = tid & 63;
    const int p = ln & 15, g = ln >> 4;
    const int wr = w4 >> 1, wc = w4 & 1;

    const int arow = w4 * 32 + (ln >> 2);       // 0..127 (this thread's 2 rows: arow, arow+16... grouped per wave)
    const int acol = (ln & 3) * 8;

    // input row sources (fixed across K-loop)
    int row0, row1;
    if (z == 0) { row0 = m0 + arow; row1 = m0 + arow + 16; }
    else {
        row0 = bb * Sn + inv[bb * Sn + s0 + arow];
        row1 = bb * Sn + inv[bb * Sn + s0 + arow + 16];
    }
    const float* ga0 = A + (size_t)row0 * Dn + acol;
    const float* ga1 = A + (size_t)row1 * Dn + acol;
    const float* gw  = W + (size_t)(n0 + arow) * Dn + acol;

    f32x4 acc[4][4];
    #pragma unroll
    for (int mi = 0; mi < 4; ++mi)
        #pragma unroll
        for (int ni = 0; ni < 4; ++ni) acc[mi][ni] = (f32x4){0.f,0.f,0.f,0.f};

    // staging registers for one K-tile
    float4 a0, a1, a2, a3, w0, w1, w2, w3;
    a0 = *(const float4*)(ga0);           a1 = *(const float4*)(ga0 + 4);
    a2 = *(const float4*)(ga1);           a3 = *(const float4*)(ga1 + 4);
    w0 = *(const float4*)(gw);            w1 = *(const float4*)(gw + 4);
    w2 = *(const float4*)(gw + 16*Dn);    w3 = *(const float4*)(gw + 16*Dn + 4);

    for (int k0 = 0; k0 < Dn; k0 += 32) {
        __syncthreads();                       // prev iter done reading LDS
        *(bf16x8*)&As [arow     ][acol] = cvt8(a0, a1);
        *(bf16x8*)&As [arow + 16][acol] = cvt8(a2, a3);
        *(bf16x8*)&Ws_[arow     ][acol] = cvt8(w0, w1);
        *(bf16x8*)&Ws_[arow + 16][acol] = cvt8(w2, w3);
        __syncthreads();                       // LDS visible

        if (k0 + 32 < Dn) {                    // next tile loads fly during MFMA
            const int k1 = k0 + 32;
            a0 = *(const float4*)(ga0 + k1);         a1 = *(const float4*)(ga0 + k1 + 4);
            a2 = *(const float4*)(ga1 + k1);         a3 = *(const float4*)(ga1 + k1 + 4);
            w0 = *(const float4*)(gw + k1);          w1 = *(const float4*)(gw + k1 + 4);
            w2 = *(const float4*)(gw + k1 + 16*Dn);  w3 = *(const float4*)(gw + k1 + 16*Dn + 4);
        }

        bf16x8 af[4], bfr[4];
        #pragma unroll
        for (int mi = 0; mi < 4; ++mi)
            af[mi] = *(const bf16x8*)&As[wr*64 + mi*16 + p][g*8];
        #pragma unroll
        for (int ni = 0; ni < 4; ++ni)
            bfr[ni] = *(const bf16x8*)&Ws_[wc*64 + ni*16 + p][g*8];
        #pragma unroll
        for (int mi = 0; mi < 4; ++mi)
            #pragma unroll
            for (int ni = 0; ni < 4; ++ni)
                acc[mi][ni] = mfma16(af[mi], bfr[ni], acc[mi][ni]);
    }

    // NOTE: As staging covers rows arow and arow+16 — rows w4*32..w4*32+31 per
    // wave across 4 waves = 0..127; af reads rows wr*64+mi*16+p — all staged.

    if (z == 0) {
        const float osc = 0.18033688011112042f;   // log2(e)/8
        #pragma unroll
        for (int ni = 0; ni < 4; ++ni) {
            int n = n0 + wc*64 + ni*16 + p;
            int h = n >> 6, dk = n & (DKn - 1);
            float bv = bias[n];
            #pragma unroll
            for (int mi = 0; mi < 4; ++mi)
                #pragma unroll
                for (int r = 0; r < 4; ++r) {
                    int m = m0 + wr*64 + mi*16 + 4*g + r;
                    int b = m >> 11, s = m & (Sn - 1);
                    C[(((size_t)(b*Hn + h)*Sn + s)*DKn) + dk] =
                        (bf16)((acc[mi][ni][r] + bv) * osc);
                }
        }
    } else if (z == 1) {     // K: direct slot-row writes (contiguous, no scatter)
        #pragma unroll
        for (int ni = 0; ni < 4; ++ni) {
            int n = n0 + wc*64 + ni*16 + p;
            int h = n >> 6, dk = n & (DKn - 1);
            float bv = bias[n];
            #pragma unroll
            for (int mi = 0; mi < 4; ++mi)
                #pragma unroll
                for (int r = 0; r < 4; ++r) {
                    int j = s0 + wr*64 + mi*16 + 4*g + r;   // slot
                    C[(((size_t)(bb*Hn + h)*Sn + j)*DKn) + dk] =
                        (bf16)(acc[mi][ni][r] + bv);
                }
        }
    } else {                 // V: [B,H,DK,slot]
        #pragma unroll
        for (int ni = 0; ni < 4; ++ni) {
            int n = n0 + wc*64 + ni*16 + p;
            int h = n >> 6, dk = n & (DKn - 1);
            float bv = bias[n];
            #pragma unroll
            for (int mi = 0; mi < 4; ++mi)
                #pragma unroll
                for (int r = 0; r < 4; ++r) {
                    int j = s0 + wr*64 + mi*16 + 4*g + r;   // slot
                    C[(((size_t)(bb*Hn + h)*DKn + dk)*Sn) + j] =
                        (bf16)(acc[mi][ni][r] + bv);
                }
        }
    }
}

// ---------- output GEMM, fused Wo conversion (r13 exact) ----------
__global__ __launch_bounds__(256)
void gemm_out(const bf16* __restrict__ A, const float* __restrict__ W,
              const float* __restrict__ bias, float* __restrict__ C)
{
    __shared__ bf16 As[128][32];
    __shared__ bf16 Ws_[64][32];

    const int bid = blockIdx.x;
    const int l   = (bid & 7) * 64 + (bid >> 3);
    const int m0  = (l >> 4) * 128;
    const int n0  = (l & 15) * 64;

    const int tid = threadIdx.x;
    const int w4 = tid >> 6, ln = tid & 63;
    const int p = ln & 15, g = ln >> 4;
    const int wr = w4 >> 1, wc = w4 & 1;

    const int arow = w4 * 32 + (ln >> 2);
    const int acol = (ln & 3) * 8;
    const bf16*  ga = A + (size_t)(m0 + arow) * Dn + acol;
    const int    lwr = w4 * 16 + (ln >> 2);
    const float* gw  = W + (size_t)(n0 + lwr) * Dn + acol;

    f32x4 acc[4][2];
    #pragma unroll
    for (int mi = 0; mi < 4; ++mi)
        #pragma unroll
        for (int ni = 0; ni < 2; ++ni) acc[mi][ni] = (f32x4){0.f,0.f,0.f,0.f};

    float4 w0, w1;
    w0 = *(const float4*)(gw);
    w1 = *(const float4*)(gw + 4);

    for (int k0 = 0; k0 < Dn; k0 += 32) {
        __syncthreads();
        *(bf16x8*)&Ws_[lwr][acol] = cvt8(w0, w1);
        glds16(ga + k0,          &As[w4*32     ][0]);
        glds16(ga + k0 + 16*Dn,  &As[w4*32 + 16][0]);
        __syncthreads();

        if (k0 + 32 < Dn) {
            w0 = *(const float4*)(gw + k0 + 32);
            w1 = *(const float4*)(gw + k0 + 36);
        }

        bf16x8 af[4], bfr[2];
        #pragma unroll
        for (int mi = 0; mi < 4; ++mi)
            af[mi] = *(const bf16x8*)&As[wr*64 + mi*16 + p][g*8];
        #pragma unroll
        for (int ni = 0; ni < 2; ++ni)
            bfr[ni] = *(const bf16x8*)&Ws_[wc*32 + ni*16 + p][g*8];
        #pragma unroll
        for (int mi = 0; mi < 4; ++mi)
            #pragma unroll
            for (int ni = 0; ni < 2; ++ni)
                acc[mi][ni] = mfma16(af[mi], bfr[ni], acc[mi][ni]);
    }

    #pragma unroll
    for (int ni = 0; ni < 2; ++ni) {
        int n = n0 + wc*32 + ni*16 + p;
        float bv = bias[n];
        #pragma unroll
        for (int mi = 0; mi < 4; ++mi)
            #pragma unroll
            for (int r = 0; r < 4; ++r) {
                int m = m0 + wr*64 + mi*16 + 4*g + r;
                C[(size_t)m * Dn + n] = acc[mi][ni][r] + bv;
            }
    }
}

// ---------- MFMA flash attention on COMPACTED keys (r13 exact) ----------
__global__ __launch_bounds__(512)
void attn_mfma(const bf16* __restrict__ Q, const bf16* __restrict__ K,
               const bf16* __restrict__ Vt, const int* __restrict__ cnt,
               bf16* __restrict__ ctx)
{
    __shared__ bf16 Ks[2][64][64];
    __shared__ bf16 Vs[2][64][64];
    __shared__ bf16 Ps[8][16][72];

    const int tid  = threadIdx.x;
    const int lane = tid & 63;
    const int w    = tid >> 6;
    const int g    = lane >> 4;
    const int p    = lane & 15;
    const int bh   = blockIdx.y;
    const int b    = bh >> 4;
    const int h    = bh & 15;
    const int q0   = blockIdx.x * 128;

    const int  cntb = cnt[b];
    const bool unif = (cntb == 0);
    const int  nt   = unif ? (Sn / 64) : ((cntb + 63) >> 6);

    const bf16* Qb = Q  + (size_t)bh * Sn * DKn;
    const bf16* Kb = K  + (size_t)bh * Sn * DKn;
    const bf16* Vb = Vt + (size_t)bh * DKn * Sn;

    const int sr   = lane >> 3;
    const int scol = 8 * ((lane & 7) ^ sr);
    const int drow = w * 8 + sr;
    const int swzk = (p & 7) << 3;
    const bf16* gK = Kb + (size_t)drow * DKn + scol;
    const bf16* gV = Vb + (size_t)drow * Sn  + scol;

    bf16x8 aq0, aq1;
    {
        const bf16* qrow = Qb + (size_t)(q0 + w*16 + p) * DKn + 8*g;
        aq0 = *(const bf16x8*)(qrow);
        aq1 = *(const bf16x8*)(qrow + 32);
    }

    f32x4 o[4];
    #pragma unroll
    for (int dt = 0; dt < 4; ++dt) o[dt] = (f32x4){0.f,0.f,0.f,0.f};
    float lq = 0.f;

    glds16(gK, &Ks[0][w*8][0]);
    glds16(gV, &Vs[0][w*8][0]);
    __syncthreads();

    int bf = 0;
    for (int kt = 0; kt < nt; ++kt) {
        if (kt + 1 < nt) {
            glds16(gK + (size_t)(kt+1)*64*DKn, &Ks[bf^1][w*8][0]);
            glds16(gV + (size_t)(kt+1)*64,     &Vs[bf^1][w*8][0]);
        }

        const bool tail = (!unif) && (kt == nt - 1);
        const int  rem  = cntb - (kt << 6);

        #pragma unroll
        for (int t = 0; t < 4; ++t) {
            f32x4 z = (f32x4){0.f,0.f,0.f,0.f};
            bf16x8 k0 = *(const bf16x8*)&Ks[bf][16*t + p][(8*g)      ^ swzk];
            bf16x8 k1 = *(const bf16x8*)&Ks[bf][16*t + p][(8*g + 32) ^ swzk];
            z = mfma16(k0, aq0, z);
            z = mfma16(k1, aq1, z);
            bf16x4 pk;
            if (unif) {
                pk[0] = (bf16)1.f; pk[1] = (bf16)1.f;
                pk[2] = (bf16)1.f; pk[3] = (bf16)1.f;
                lq += 4.f;
            } else if (tail) {
                int kb = 16*t + 4*g;
                pk[0] = (bf16)(kb + 0 < rem ? exp2f(z[0]) : 0.f);
                pk[1] = (bf16)(kb + 1 < rem ? exp2f(z[1]) : 0.f);
                pk[2] = (bf16)(kb + 2 < rem ? exp2f(z[2]) : 0.f);
                pk[3] = (bf16)(kb + 3 < rem ? exp2f(z[3]) : 0.f);
                lq += (float)pk[0] + (float)pk[1] + (float)pk[2] + (float)pk[3];
            } else {
                pk[0] = (bf16)exp2f(z[0]);
                pk[1] = (bf16)exp2f(z[1]);
                pk[2] = (bf16)exp2f(z[2]);
                pk[3] = (bf16)exp2f(z[3]);
                lq += (float)pk[0] + (float)pk[1] + (float)pk[2] + (float)pk[3];
            }
            *(bf16x4*)&Ps[w][p][16*t + 4*g] = pk;
        }

        bf16x8 pa0 = *(const bf16x8*)&Ps[w][p][8*g];
        bf16x8 pa1 = *(const bf16x8*)&Ps[w][p][32 + 8*g];
        #pragma unroll
        for (int dt = 0; dt < 4; ++dt) {
            bf16x8 v0 = *(const bf16x8*)&Vs[bf][16*dt + p][(8*g)      ^ swzk];
            bf16x8 v1 = *(const bf16x8*)&Vs[bf][16*dt + p][(8*g + 32) ^ swzk];
            o[dt] = mfma16(pa0, v0, o[dt]);
            o[dt] = mfma16(pa1, v1, o[dt]);
        }

        __syncthreads();
        bf ^= 1;
    }

    lq += __shfl_xor(lq, 16);
    lq += __shfl_xor(lq, 32);
    float ld[4];
    #pragma unroll
    for (int r = 0; r < 4; ++r) ld[r] = __shfl(lq, 4*g + r);

    #pragma unroll
    for (int dt = 0; dt < 4; ++dt)
        #pragma unroll
        for (int r = 0; r < 4; ++r) {
            int s_ = q0 + w*16 + 4*g + r;
            ctx[(size_t)(b*Sn + s_) * Dn + h*64 + 16*dt + p] =
                (bf16)(o[dt][r] / ld[r]);
        }
}

extern "C" void kernel_launch(void* const* d_in, const int* in_sizes, int n_in,
                              void* d_out, int out_size, void* d_ws, size_t ws_size,
                              hipStream_t stream) {
    const float* q_in = (const float*)d_in[0];
    const float* k_in = (const float*)d_in[1];
    const float* v_in = (const float*)d_in[2];
    const int*   mask = (const int*)  d_in[3];
    const float* w_q  = (const float*)d_in[4];
    const float* b_q  = (const float*)d_in[5];
    const float* w_k  = (const float*)d_in[6];
    const float* b_k  = (const float*)d_in[7];
    const float* w_v  = (const float*)d_in[8];
    const float* b_v  = (const float*)d_in[9];
    const float* w_o  = (const float*)d_in[10];
    const float* b_o  = (const float*)d_in[11];

    // ws: ctx 8.39MB | Qh 8.39 | Kh 8.39 | Vt 8.39 | inv 16KB | cnt. ~33.6MB.
    char* ws = (char*)d_ws;
    bf16* ctx  = (bf16*)(ws);
    bf16* Qh   = (bf16*)(ws + 8388608);
    bf16* Kh   = (bf16*)(ws + 16777216);
    bf16* Vt   = (bf16*)(ws + 25165824);
    int*  inv  = (int*) (ws + 33554432);
    int*  cntb = (int*) (ws + 33570816);

    dim3 blk(256);
    mask_scan<<<dim3(Bn), dim3(64), 0, stream>>>(mask, inv, cntb);

    gemm_proj<<<dim3(768), blk, 0, stream>>>(
        q_in, k_in, v_in, w_q, w_k, w_v, b_q, b_k, b_v, inv, cntb, Qh, Kh, Vt);

    attn_mfma<<<dim3(Sn/128, Bn*Hn), dim3(512), 0, stream>>>(Qh, Kh, Vt, cntb, ctx);

    gemm_out<<<dim3(512), blk, 0, stream>>>(ctx, w_o, b_o, (float*)d_out);
}